// Round 3
// baseline (428.558 us; speedup 1.0000x reference)
//
#include <hip/hip_runtime.h>

typedef __bf16 bf16x8 __attribute__((ext_vector_type(8)));
typedef float f32x4 __attribute__((ext_vector_type(4)));
typedef unsigned short us4 __attribute__((ext_vector_type(4)));

constexpr int TT = 2048;   // tokens
constexpr int CC = 2048;   // channels
constexpr int HH = 16;     // heads
constexpr int DD = 128;    // head dim

__device__ __forceinline__ unsigned short f2bf(float f) {
  unsigned u = __builtin_bit_cast(unsigned, f);
  u += 0x7FFFu + ((u >> 16) & 1u);
  return (unsigned short)(u >> 16);
}
__device__ __forceinline__ float bf2f(unsigned short b) {
  unsigned u = ((unsigned)b) << 16;
  return __builtin_bit_cast(float, u);
}

// async global->LDS, 16B per lane. C-style casts lower to addrspacecast.
__device__ __forceinline__ void gld_lds16(const unsigned short* g, unsigned short* l) {
  __builtin_amdgcn_global_load_lds(
      (const __attribute__((address_space(1))) unsigned int*)g,
      (__attribute__((address_space(3))) unsigned int*)l,
      16, 0, 0);
}

// compact split-slot table: ns(qt) = qt/8+1, off(qt) = sum of ns below qt
__device__ __host__ __forceinline__ int slot_off(int qt) {
  int g = qt >> 3, rem = qt & 7;
  return (g + 1) * (4 * g + rem);
}

// ---------------- f32 -> bf16 convert ----------------
__global__ __launch_bounds__(256) void k_f32_to_bf16(
    const float* __restrict__ src, unsigned short* __restrict__ dst, int n8) {
  int i = blockIdx.x * 256 + threadIdx.x;
  if (i >= n8) return;
  const float4* s = (const float4*)src;
  float4 a = s[2 * i], b = s[2 * i + 1];
  us4 lo = { f2bf(a.x), f2bf(a.y), f2bf(a.z), f2bf(a.w) };
  us4 hi = { f2bf(b.x), f2bf(b.y), f2bf(b.z), f2bf(b.w) };
  us4* d = (us4*)dst;
  d[2 * i] = lo;
  d[2 * i + 1] = hi;
}

// ---------------- GEMM: C = A(MxK) * B(NxK)^T, bf16 in, f32 out ----------------
template <int MODE>
__global__ __launch_bounds__(256) void k_gemm_bt(
    const unsigned short* __restrict__ A, const unsigned short* __restrict__ B,
    int M, int N, int K,
    float* __restrict__ out0, float* __restrict__ out1, float* __restrict__ out2) {
  __shared__ alignas(16) unsigned short As[128 * 64];
  __shared__ alignas(16) unsigned short Bs[128 * 64];
  const int tid = threadIdx.x;
  const int m0 = blockIdx.y * 128, n0 = blockIdx.x * 128;
  const int wid = tid >> 6, lane = tid & 63;
  const int wm = (wid >> 1) * 64, wn = (wid & 1) * 64;
  const int lr = lane & 15, lg = lane >> 4;
  f32x4 acc[4][4] = {};
  const int rowS = tid >> 3;        // 0..31 (+i*32)
  const int colS = (tid & 7) * 8;   // 0,8,..,56
  const unsigned short* ag = A + (size_t)(m0 + rowS) * K + colS;
  const unsigned short* bg = B + (size_t)(n0 + rowS) * K + colS;

  for (int k0 = 0; k0 < K; k0 += 64) {
#pragma unroll
    for (int i = 0; i < 4; ++i)
      gld_lds16(ag + (size_t)(i * 32) * K + k0, As + tid * 8 + i * 2048);
#pragma unroll
    for (int i = 0; i < 4; ++i)
      gld_lds16(bg + (size_t)(i * 32) * K + k0, Bs + tid * 8 + i * 2048);
    __syncthreads();
#pragma unroll
    for (int ks = 0; ks < 2; ++ks) {
      bf16x8 av[4], bv[4];
#pragma unroll
      for (int m = 0; m < 4; ++m)
        av[m] = *(const bf16x8*)(As + (wm + m * 16 + lr) * 64 + ks * 32 + lg * 8);
#pragma unroll
      for (int n = 0; n < 4; ++n)
        bv[n] = *(const bf16x8*)(Bs + (wn + n * 16 + lr) * 64 + ks * 32 + lg * 8);
#pragma unroll
      for (int m = 0; m < 4; ++m)
#pragma unroll
        for (int n = 0; n < 4; ++n)
          acc[m][n] = __builtin_amdgcn_mfma_f32_16x16x32_bf16(av[m], bv[n], acc[m][n], 0, 0, 0);
    }
    __syncthreads();
  }

#pragma unroll
  for (int m = 0; m < 4; ++m) {
    const int row = m0 + wm + m * 16 + lg * 4;
#pragma unroll
    for (int n = 0; n < 4; ++n) {
      const int col = n0 + wn + n * 16 + lr;
#pragma unroll
      for (int r = 0; r < 4; ++r) {
        float v = acc[m][n][r];
        int rr = row + r;
        if (MODE == 0) {
          if (col < 2048) {
            out0[(size_t)rr * 2048 + col] = v;
          } else if (col < 4096) {
            int c = col - 2048;
            out1[(size_t)(c >> 7) * (TT * DD) + (size_t)rr * DD + (c & 127)] = v;
          } else {
            int c = col - 4096;
            out2[(size_t)(c >> 7) * (TT * DD) + (size_t)rr * DD + (c & 127)] = v;
          }
        } else {
          out0[(size_t)rr * N + col] = v;
        }
      }
    }
  }
}

// ---------------- RoPE + scale, pack q/k as bf16 [h][t][d] ----------------
__global__ __launch_bounds__(256) void k_rope(
    const float* __restrict__ Qf, const float* __restrict__ Kraw,
    const float* __restrict__ sqk,
    unsigned short* __restrict__ qb, unsigned short* __restrict__ kb) {
  const int t = blockIdx.x;
  for (int i = threadIdx.x; i < HH * 64; i += 256) {
    int h = i >> 6, dp = i & 63;
    float theta = expf(-(float)dp * 0.14391156831212787f);
    float ang = (float)t * theta;
    float sn, cs;
    sincosf(ang, &sn, &cs);
    float qr = Qf[(size_t)t * CC + h * DD + dp];
    float qi = Qf[(size_t)t * CC + h * DD + dp + 64];
    const float* kp = Kraw + (size_t)h * TT * DD + (size_t)t * DD;
    float kr = kp[dp], ki = kp[dp + 64];
    float sr = sqk[h * DD + dp];
    float si = sqk[h * DD + dp + 64];
    float qsr = sr * 512.0f, qsi = si * 512.0f;                       // sqrt(C)*sqrt(D)
    float ksr = sr * 45.25483399593904f, ksi = si * 45.25483399593904f; // sqrt(C)
    unsigned short* qo = qb + ((size_t)h * TT + t) * DD;
    unsigned short* ko = kb + ((size_t)h * TT + t) * DD;
    qo[dp]      = f2bf((qr * cs - qi * sn) * qsr);
    qo[dp + 64] = f2bf((qr * sn + qi * cs) * qsi);
    ko[dp]      = f2bf((kr * cs - ki * sn) * ksr);
    ko[dp + 64] = f2bf((kr * sn + ki * cs) * ksi);
  }
}

// ---------------- V transpose: new_v f32 [h][t][d] -> vt bf16 [h][d][t] ----------------
__global__ __launch_bounds__(256) void k_vt(
    const float* __restrict__ Vraw, unsigned short* __restrict__ vt) {
  const int h = blockIdx.z;
  const int t0 = blockIdx.x * 64, d0 = blockIdx.y * 64;
  __shared__ unsigned short tile[64][65];
  const float* vp = Vraw + (size_t)h * TT * DD;
  for (int i = threadIdx.x; i < 4096; i += 256) {
    int r = i >> 6, c = i & 63;
    tile[r][c] = f2bf(vp[(size_t)(t0 + r) * DD + d0 + c]);
  }
  __syncthreads();
  unsigned short* op = vt + (size_t)h * DD * TT;
  for (int i = threadIdx.x; i < 4096; i += 256) {
    int dr = i >> 6, tc = i & 63;
    op[(size_t)(d0 + dr) * TT + t0 + tc] = tile[tc][dr];
  }
}

// ---------------- causal flash attention, split-K (flash-decoding) ----------------
// grid (32 qtiles, 16 heads, 4 ksplits); 256 threads = 4 independent waves.
// Split s covers keys [512s, min(512(s+1), 64qt+64)); inactive splits exit.
// Writes unnormalized partial O (bf16) + per-row m,l (f32) into compact slots.
__global__ __launch_bounds__(256) void k_attn_split(
    const unsigned short* __restrict__ qb, const unsigned short* __restrict__ kb,
    const unsigned short* __restrict__ vt,
    unsigned short* __restrict__ po, float* __restrict__ marr, float* __restrict__ larr) {
  const int qt = blockIdx.x, h = blockIdx.y, s = blockIdx.z;
  if (8 * s > qt) return;  // inactive split (uniform block exit, before any barrier)
  const int slot = h * 80 + slot_off(qt) + s;
  const int kbeg = 512 * s;
  const int kend = min(512 * (s + 1), 64 * qt + 64);
  const int wid = threadIdx.x >> 6, lane = threadIdx.x & 63;
  const int lr = lane & 15, lg = lane >> 4;
  __shared__ alignas(16) unsigned short P[4][16][40];
  const int q0 = qt * 64 + wid * 16;
  const unsigned short* qh = qb + (size_t)h * TT * DD;
  const unsigned short* kh = kb + (size_t)h * TT * DD;
  const unsigned short* vh = vt + (size_t)h * DD * TT;

  bf16x8 qf[4];
#pragma unroll
  for (int c = 0; c < 4; ++c)
    qf[c] = *(const bf16x8*)(qh + (size_t)(q0 + lr) * DD + c * 32 + lg * 8);

  f32x4 acc[8] = {};
  float mrow[4] = {-3e38f, -3e38f, -3e38f, -3e38f};
  float lsum[4] = {0.f, 0.f, 0.f, 0.f};

  for (int k0 = kbeg; k0 < kend && k0 <= q0 + 15; k0 += 32) {
    f32x4 s0 = {}, s1 = {};
#pragma unroll
    for (int c = 0; c < 4; ++c) {
      bf16x8 kf0 = *(const bf16x8*)(kh + (size_t)(k0 + lr) * DD + c * 32 + lg * 8);
      bf16x8 kf1 = *(const bf16x8*)(kh + (size_t)(k0 + 16 + lr) * DD + c * 32 + lg * 8);
      s0 = __builtin_amdgcn_mfma_f32_16x16x32_bf16(qf[c], kf0, s0, 0, 0, 0);
      s1 = __builtin_amdgcn_mfma_f32_16x16x32_bf16(qf[c], kf1, s1, 0, 0, 0);
    }
    if (k0 + 31 > q0) {  // diagonal tiles need causal masking
#pragma unroll
      for (int r = 0; r < 4; ++r) {
        int rt = q0 + lg * 4 + r;
        if (k0 + lr > rt) s0[r] = -1e30f;
        if (k0 + 16 + lr > rt) s1[r] = -1e30f;
      }
    }
    float pmax[4];
#pragma unroll
    for (int r = 0; r < 4; ++r) pmax[r] = fmaxf(s0[r], s1[r]);
#pragma unroll
    for (int msk = 1; msk <= 8; msk <<= 1)
#pragma unroll
      for (int r = 0; r < 4; ++r) pmax[r] = fmaxf(pmax[r], __shfl_xor(pmax[r], msk));
    float p0[4], p1[4], ps[4], scl[4];
#pragma unroll
    for (int r = 0; r < 4; ++r) {
      float mn = fmaxf(mrow[r], pmax[r]);
      scl[r] = __expf(mrow[r] - mn);
      mrow[r] = mn;
      p0[r] = __expf(s0[r] - mn);
      p1[r] = __expf(s1[r] - mn);
      ps[r] = p0[r] + p1[r];
    }
#pragma unroll
    for (int msk = 1; msk <= 8; msk <<= 1)
#pragma unroll
      for (int r = 0; r < 4; ++r) ps[r] += __shfl_xor(ps[r], msk);
#pragma unroll
    for (int r = 0; r < 4; ++r) lsum[r] = lsum[r] * scl[r] + ps[r];
#pragma unroll
    for (int n = 0; n < 8; ++n)
#pragma unroll
      for (int r = 0; r < 4; ++r) acc[n][r] *= scl[r];
#pragma unroll
    for (int r = 0; r < 4; ++r) {
      P[wid][lg * 4 + r][lr]      = f2bf(p0[r]);
      P[wid][lg * 4 + r][16 + lr] = f2bf(p1[r]);
    }
    asm volatile("s_waitcnt lgkmcnt(0)" ::: "memory");
    bf16x8 pf = *(const bf16x8*)(&P[wid][lr][lg * 8]);
#pragma unroll
    for (int n = 0; n < 8; ++n) {
      bf16x8 vf = *(const bf16x8*)(vh + (size_t)(n * 16 + lr) * TT + k0 + lg * 8);
      acc[n] = __builtin_amdgcn_mfma_f32_16x16x32_bf16(pf, vf, acc[n], 0, 0, 0);
    }
  }

  // write unnormalized partial: O~, m, l
  unsigned short* pob = po + (size_t)slot * (64 * DD);
#pragma unroll
  for (int n = 0; n < 8; ++n)
#pragma unroll
    for (int r = 0; r < 4; ++r) {
      int row = wid * 16 + lg * 4 + r;
      pob[(size_t)row * DD + n * 16 + lr] = f2bf(acc[n][r]);
    }
  if (lr == 0) {
#pragma unroll
    for (int r = 0; r < 4; ++r) {
      int row = wid * 16 + lg * 4 + r;
      marr[(size_t)slot * 64 + row] = mrow[r];
      larr[(size_t)slot * 64 + row] = lsum[r];
    }
  }
}

// ---------------- split reduce: combine <=4 partials, normalize, emit bf16 ----------------
__global__ __launch_bounds__(256) void k_attn_reduce(
    const unsigned short* __restrict__ po, const float* __restrict__ marr,
    const float* __restrict__ larr, unsigned short* __restrict__ ob) {
  const int qt = blockIdx.x, h = blockIdx.y;
  const int ns = (qt >> 3) + 1;
  const int sb = h * 80 + slot_off(qt);
  const int t = threadIdx.x;
  const int r = t >> 2, cq = (t & 3) * 32;
  float mstar = -3e38f;
  for (int s = 0; s < ns; ++s) mstar = fmaxf(mstar, marr[(size_t)(sb + s) * 64 + r]);
  float w[4];
  float ltot = 0.f;
  for (int s = 0; s < ns; ++s) {
    w[s] = __expf(marr[(size_t)(sb + s) * 64 + r] - mstar);
    ltot += w[s] * larr[(size_t)(sb + s) * 64 + r];
  }
  float inv = 1.0f / ltot;
  float o[32] = {};
  for (int s = 0; s < ns; ++s) {
    const unsigned short* pp = po + (size_t)(sb + s) * (64 * DD) + (size_t)r * DD + cq;
    float ws = w[s];
#pragma unroll
    for (int c = 0; c < 32; ++c) o[c] += ws * bf2f(pp[c]);
  }
  unsigned short* op = ob + (size_t)(qt * 64 + r) * CC + h * DD + cq;
  us4 v[8];
#pragma unroll
  for (int c = 0; c < 32; ++c) ((unsigned short*)v)[c] = f2bf(o[c] * inv);
#pragma unroll
  for (int j = 0; j < 8; ++j) ((us4*)op)[j] = v[j];
}

// ---------------- row l2norm ----------------
__global__ __launch_bounds__(256) void k_l2norm(
    const float* __restrict__ Of, float* __restrict__ out) {
  const int t = blockIdx.x;
  const int tid = threadIdx.x;
  const float4* p = (const float4*)(Of + (size_t)t * CC);
  float4 a = p[2 * tid], b = p[2 * tid + 1];
  float ss = a.x * a.x + a.y * a.y + a.z * a.z + a.w * a.w +
             b.x * b.x + b.y * b.y + b.z * b.z + b.w * b.w;
#pragma unroll
  for (int msk = 1; msk < 64; msk <<= 1) ss += __shfl_xor(ss, msk);
  __shared__ float red[4];
  if ((tid & 63) == 0) red[tid >> 6] = ss;
  __syncthreads();
  ss = red[0] + red[1] + red[2] + red[3];
  float sc = 1.0f / fmaxf(sqrtf(ss), 1e-12f);
  float4 oa = { a.x * sc, a.y * sc, a.z * sc, a.w * sc };
  float4 obv = { b.x * sc, b.y * sc, b.z * sc, b.w * sc };
  float4* o = (float4*)(out + (size_t)t * CC);
  o[2 * tid] = oa;
  o[2 * tid + 1] = obv;
}

extern "C" void kernel_launch(void* const* d_in, const int* in_sizes, int n_in,
                              void* d_out, int out_size, void* d_ws, size_t ws_size,
                              hipStream_t stream) {
  const float* x   = (const float*)d_in[0];
  const float* wq  = (const float*)d_in[1];
  const float* wk  = (const float*)d_in[2];
  const float* wv  = (const float*)d_in[3];
  const float* wo  = (const float*)d_in[4];
  const float* sqk = (const float*)d_in[5];

  float* out_norm = (float*)d_out;                                  // 4M f32
  float* out_k = out_norm + (size_t)4 * 1024 * 1024;                // new_k (h,t,d)
  float* out_v = out_norm + (size_t)8 * 1024 * 1024;                // new_v (h,t,d)

  char* ws = (char*)d_ws;
  unsigned short* xb  = (unsigned short*)(ws);                      // 0..8MB  (free after QKV GEMM)
  unsigned short* w1b = (unsigned short*)(ws + (8u << 20));         // 8..32MB (free after QKV GEMM)
  unsigned short* wob = (unsigned short*)(ws + (32u << 20));        // 32..40MB
  unsigned short* qb  = (unsigned short*)(ws + (40u << 20));        // 40..48MB
  unsigned short* kb  = (unsigned short*)(ws + (48u << 20));        // 48..56MB
  unsigned short* vtb = (unsigned short*)(ws + (56u << 20));        // 56..64MB
  unsigned short* obb = (unsigned short*)(ws + (64u << 20));        // 64..72MB
  float* Qf = (float*)(ws + (72u << 20));                           // 72..88MB (Q f32, reused as Of)

  // attention split partials: reuse 0..32MB region (xb+w1b dead after QKV GEMM)
  unsigned short* po = (unsigned short*)(ws);                       // 16*80 slots * 64*128 bf16 = 21MB
  float* marr = (float*)(ws + (22u << 20));                         // 0.31MB
  float* larr = (float*)(ws + (23u << 20));                         // 0.31MB

  const int n8 = (CC * CC) / 8;
  k_f32_to_bf16<<<n8 / 256, 256, 0, stream>>>(x,  xb, n8);
  k_f32_to_bf16<<<n8 / 256, 256, 0, stream>>>(wq, w1b, n8);
  k_f32_to_bf16<<<n8 / 256, 256, 0, stream>>>(wk, w1b + (size_t)4 * 1024 * 1024, n8);
  k_f32_to_bf16<<<n8 / 256, 256, 0, stream>>>(wv, w1b + (size_t)8 * 1024 * 1024, n8);
  k_f32_to_bf16<<<n8 / 256, 256, 0, stream>>>(wo, wob, n8);

  // fused QKV projection: C = x @ [wq;wk;wv]^T  (2048 x 6144)
  k_gemm_bt<0><<<dim3(48, 16), 256, 0, stream>>>(xb, w1b, TT, 3 * CC, CC, Qf, out_k, out_v);

  k_rope<<<TT, 256, 0, stream>>>(Qf, out_k, sqk, qb, kb);
  k_vt<<<dim3(32, 2, 16), 256, 0, stream>>>(out_v, vtb);

  k_attn_split<<<dim3(32, 16, 4), 256, 0, stream>>>(qb, kb, vtb, po, marr, larr);
  k_attn_reduce<<<dim3(32, 16), 256, 0, stream>>>(po, marr, larr, obb);

  // output projection: Of = attn_out @ wo^T
  k_gemm_bt<1><<<dim3(16, 16), 256, 0, stream>>>(obb, wob, TT, CC, CC, Qf, nullptr, nullptr);

  k_l2norm<<<TT, 256, 0, stream>>>(Qf, out_norm);
}

// Round 4
// 274.258 us; speedup vs baseline: 1.5626x; 1.5626x over previous
//
#include <hip/hip_runtime.h>

typedef __bf16 bf16x8 __attribute__((ext_vector_type(8)));
typedef float f32x4 __attribute__((ext_vector_type(4)));
typedef unsigned short us4 __attribute__((ext_vector_type(4)));

constexpr int TT = 2048;   // tokens
constexpr int CC = 2048;   // channels
constexpr int HH = 16;     // heads
constexpr int DD = 128;    // head dim

__device__ __forceinline__ unsigned short f2bf(float f) {
  unsigned u = __builtin_bit_cast(unsigned, f);
  u += 0x7FFFu + ((u >> 16) & 1u);
  return (unsigned short)(u >> 16);
}
__device__ __forceinline__ float bf2f(unsigned short b) {
  unsigned u = ((unsigned)b) << 16;
  return __builtin_bit_cast(float, u);
}

// async global->LDS, 16B per lane. C-style casts lower to addrspacecast.
__device__ __forceinline__ void gld_lds16(const unsigned short* g, unsigned short* l) {
  __builtin_amdgcn_global_load_lds(
      (const __attribute__((address_space(1))) unsigned int*)g,
      (__attribute__((address_space(3))) unsigned int*)l,
      16, 0, 0);
}

// split-slot table for QBLK=128, SPLIT=512 keys: ns(qt)=qt/4+1, 40 slots/head
__device__ __forceinline__ int soff(int qt) {
  int g = qt >> 2, rem = qt & 3;
  return (g + 1) * (2 * g + rem);
}

// ---------------- f32 -> bf16 convert ----------------
__global__ __launch_bounds__(256) void k_f32_to_bf16(
    const float* __restrict__ src, unsigned short* __restrict__ dst, int n8) {
  int i = blockIdx.x * 256 + threadIdx.x;
  if (i >= n8) return;
  const float4* s = (const float4*)src;
  float4 a = s[2 * i], b = s[2 * i + 1];
  us4 lo = { f2bf(a.x), f2bf(a.y), f2bf(a.z), f2bf(a.w) };
  us4 hi = { f2bf(b.x), f2bf(b.y), f2bf(b.z), f2bf(b.w) };
  us4* d = (us4*)dst;
  d[2 * i] = lo;
  d[2 * i + 1] = hi;
}

// ---------------- GEMM: C = A(MxK) * B(NxK)^T, bf16 in, f32 out ----------------
template <int MODE>
__global__ __launch_bounds__(256) void k_gemm_bt(
    const unsigned short* __restrict__ A, const unsigned short* __restrict__ B,
    int M, int N, int K,
    float* __restrict__ out0, float* __restrict__ out1, float* __restrict__ out2) {
  __shared__ alignas(16) unsigned short As[128 * 64];
  __shared__ alignas(16) unsigned short Bs[128 * 64];
  const int tid = threadIdx.x;
  const int m0 = blockIdx.y * 128, n0 = blockIdx.x * 128;
  const int wid = tid >> 6, lane = tid & 63;
  const int wm = (wid >> 1) * 64, wn = (wid & 1) * 64;
  const int lr = lane & 15, lg = lane >> 4;
  f32x4 acc[4][4] = {};
  const int rowS = tid >> 3;
  const int colS = (tid & 7) * 8;
  const unsigned short* ag = A + (size_t)(m0 + rowS) * K + colS;
  const unsigned short* bg = B + (size_t)(n0 + rowS) * K + colS;

  for (int k0 = 0; k0 < K; k0 += 64) {
#pragma unroll
    for (int i = 0; i < 4; ++i)
      gld_lds16(ag + (size_t)(i * 32) * K + k0, As + tid * 8 + i * 2048);
#pragma unroll
    for (int i = 0; i < 4; ++i)
      gld_lds16(bg + (size_t)(i * 32) * K + k0, Bs + tid * 8 + i * 2048);
    __syncthreads();
#pragma unroll
    for (int ks = 0; ks < 2; ++ks) {
      bf16x8 av[4], bv[4];
#pragma unroll
      for (int m = 0; m < 4; ++m)
        av[m] = *(const bf16x8*)(As + (wm + m * 16 + lr) * 64 + ks * 32 + lg * 8);
#pragma unroll
      for (int n = 0; n < 4; ++n)
        bv[n] = *(const bf16x8*)(Bs + (wn + n * 16 + lr) * 64 + ks * 32 + lg * 8);
#pragma unroll
      for (int m = 0; m < 4; ++m)
#pragma unroll
        for (int n = 0; n < 4; ++n)
          acc[m][n] = __builtin_amdgcn_mfma_f32_16x16x32_bf16(av[m], bv[n], acc[m][n], 0, 0, 0);
    }
    __syncthreads();
  }

#pragma unroll
  for (int m = 0; m < 4; ++m) {
    const int row = m0 + wm + m * 16 + lg * 4;
#pragma unroll
    for (int n = 0; n < 4; ++n) {
      const int col = n0 + wn + n * 16 + lr;
#pragma unroll
      for (int r = 0; r < 4; ++r) {
        float v = acc[m][n][r];
        int rr = row + r;
        if (MODE == 0) {
          if (col < 2048) {
            out0[(size_t)rr * 2048 + col] = v;
          } else if (col < 4096) {
            int c = col - 2048;
            out1[(size_t)(c >> 7) * (TT * DD) + (size_t)rr * DD + (c & 127)] = v;
          } else {
            int c = col - 4096;
            out2[(size_t)(c >> 7) * (TT * DD) + (size_t)rr * DD + (c & 127)] = v;
          }
        } else {
          out0[(size_t)rr * N + col] = v;
        }
      }
    }
  }
}

// ---------------- RoPE + scale, pack q/k as bf16 [h][t][d] ----------------
__global__ __launch_bounds__(256) void k_rope(
    const float* __restrict__ Qf, const float* __restrict__ Kraw,
    const float* __restrict__ sqk,
    unsigned short* __restrict__ qb, unsigned short* __restrict__ kb) {
  const int t = blockIdx.x;
  for (int i = threadIdx.x; i < HH * 64; i += 256) {
    int h = i >> 6, dp = i & 63;
    float theta = expf(-(float)dp * 0.14391156831212787f);
    float ang = (float)t * theta;
    float sn, cs;
    sincosf(ang, &sn, &cs);
    float qr = Qf[(size_t)t * CC + h * DD + dp];
    float qi = Qf[(size_t)t * CC + h * DD + dp + 64];
    const float* kp = Kraw + (size_t)h * TT * DD + (size_t)t * DD;
    float kr = kp[dp], ki = kp[dp + 64];
    float sr = sqk[h * DD + dp];
    float si = sqk[h * DD + dp + 64];
    float qsr = sr * 512.0f, qsi = si * 512.0f;                         // sqrt(C)*sqrt(D)
    float ksr = sr * 45.25483399593904f, ksi = si * 45.25483399593904f; // sqrt(C)
    unsigned short* qo = qb + ((size_t)h * TT + t) * DD;
    unsigned short* ko = kb + ((size_t)h * TT + t) * DD;
    qo[dp]      = f2bf((qr * cs - qi * sn) * qsr);
    qo[dp + 64] = f2bf((qr * sn + qi * cs) * qsi);
    ko[dp]      = f2bf((kr * cs - ki * sn) * ksr);
    ko[dp + 64] = f2bf((kr * sn + ki * cs) * ksi);
  }
}

// ---------------- V transpose: new_v f32 [h][t][d] -> vt bf16 [h][d][t] ----------------
__global__ __launch_bounds__(256) void k_vt(
    const float* __restrict__ Vraw, unsigned short* __restrict__ vt) {
  const int h = blockIdx.z;
  const int t0 = blockIdx.x * 64, d0 = blockIdx.y * 64;
  __shared__ unsigned short tile[64][65];
  const float* vp = Vraw + (size_t)h * TT * DD;
  for (int i = threadIdx.x; i < 4096; i += 256) {
    int r = i >> 6, c = i & 63;
    tile[r][c] = f2bf(vp[(size_t)(t0 + r) * DD + d0 + c]);
  }
  __syncthreads();
  unsigned short* op = vt + (size_t)h * DD * TT;
  for (int i = threadIdx.x; i < 4096; i += 256) {
    int dr = i >> 6, tc = i & 63;
    op[(size_t)(d0 + dr) * TT + t0 + tc] = tile[tc][dr];
  }
}

// ---------------- causal flash attention, 8-wave LDS-staged, split-K ----------------
// grid (16 qtiles of 128 rows, 16 heads, 4 splits of 512 keys); 512 threads.
// K tile [64][128] and V^T tile [128][64] staged in LDS with XOR chunk swizzle
// (pre-swizzled global source, rule #21); each wave owns 16 q-rows.
__global__ __launch_bounds__(512) void k_attn_split(
    const unsigned short* __restrict__ qb, const unsigned short* __restrict__ kb,
    const unsigned short* __restrict__ vt,
    unsigned short* __restrict__ po, float* __restrict__ marr, float* __restrict__ larr) {
  const int qt = blockIdx.x, h = blockIdx.y, s = blockIdx.z;
  if (4 * s > qt) return;  // block-uniform exit before any barrier
  const int slot = h * 40 + soff(qt) + s;
  const int kbeg = 512 * s;
  const int kend = min(kbeg + 512, 128 * qt + 128);
  const int ntiles = (kend - kbeg) >> 6;
  const int tid = threadIdx.x;
  const int wid = tid >> 6, lane = tid & 63;
  const int lr = lane & 15, lg = lane >> 4;
  const int q0 = qt * 128 + wid * 16;

  __shared__ alignas(16) unsigned short Ks[64 * 128];   // swizzled K tile
  __shared__ alignas(16) unsigned short Vs[128 * 64];   // swizzled V^T tile
  __shared__ alignas(16) unsigned short P[8][16][72];   // per-wave P (2-way free)

  const unsigned short* qh = qb + (size_t)h * TT * DD;
  const unsigned short* kh = kb + (size_t)h * TT * DD;
  const unsigned short* vh = vt + (size_t)h * DD * TT;

  bf16x8 qf[4];
#pragma unroll
  for (int c = 0; c < 4; ++c)
    qf[c] = *(const bf16x8*)(qh + (size_t)(q0 + lr) * DD + c * 32 + lg * 8);

  f32x4 acc[8] = {};
  float mrow[4] = {-3e38f, -3e38f, -3e38f, -3e38f};
  float lsum[4] = {0.f, 0.f, 0.f, 0.f};

  for (int kt = 0; kt < ntiles; ++kt) {
    const int k0 = kbeg + kt * 64;
    // ---- stage K (1024 chunks) + V^T (1024 chunks), pre-swizzled source ----
#pragma unroll
    for (int half = 0; half < 2; ++half) {
      int ch = tid + half * 512;
      int r = ch >> 4, c4 = ch & 15;
      gld_lds16(kh + (size_t)(k0 + r) * DD + ((c4 ^ (r & 7)) * 8), Ks + ch * 8);
    }
#pragma unroll
    for (int half = 0; half < 2; ++half) {
      int ch = tid + half * 512;
      int d = ch >> 3, c8 = ch & 7;
      gld_lds16(vh + (size_t)d * TT + k0 + ((c8 ^ (d & 7)) * 8), Vs + ch * 8);
    }
    __syncthreads();

    if (k0 <= q0 + 15) {  // wave has >=1 unmasked row in this tile
      f32x4 sv[4] = {};
#pragma unroll
      for (int ktile = 0; ktile < 4; ++ktile) {
        const int row = ktile * 16 + lr;
#pragma unroll
        for (int c = 0; c < 4; ++c) {
          int chn = (c * 4 + lg) ^ (lr & 7);
          bf16x8 kf = *(const bf16x8*)(Ks + row * 128 + chn * 8);
          sv[ktile] = __builtin_amdgcn_mfma_f32_16x16x32_bf16(qf[c], kf, sv[ktile], 0, 0, 0);
        }
      }
      if (k0 + 63 > q0) {  // causal mask on diagonal tiles
#pragma unroll
        for (int ktile = 0; ktile < 4; ++ktile)
#pragma unroll
          for (int r = 0; r < 4; ++r) {
            int key = k0 + ktile * 16 + lr;
            int qrow = q0 + lg * 4 + r;
            if (key > qrow) sv[ktile][r] = -1e30f;
          }
      }
      // ---- online softmax over 64 keys ----
      float pmax[4];
#pragma unroll
      for (int r = 0; r < 4; ++r)
        pmax[r] = fmaxf(fmaxf(sv[0][r], sv[1][r]), fmaxf(sv[2][r], sv[3][r]));
#pragma unroll
      for (int msk = 1; msk <= 8; msk <<= 1)
#pragma unroll
        for (int r = 0; r < 4; ++r) pmax[r] = fmaxf(pmax[r], __shfl_xor(pmax[r], msk));
      float p[4][4], ps[4], scl[4];
#pragma unroll
      for (int r = 0; r < 4; ++r) {
        float mn = fmaxf(mrow[r], pmax[r]);
        scl[r] = __expf(mrow[r] - mn);
        mrow[r] = mn;
        ps[r] = 0.f;
#pragma unroll
        for (int ktile = 0; ktile < 4; ++ktile) {
          p[ktile][r] = __expf(sv[ktile][r] - mn);
          ps[r] += p[ktile][r];
        }
      }
#pragma unroll
      for (int msk = 1; msk <= 8; msk <<= 1)
#pragma unroll
        for (int r = 0; r < 4; ++r) ps[r] += __shfl_xor(ps[r], msk);
#pragma unroll
      for (int r = 0; r < 4; ++r) lsum[r] = lsum[r] * scl[r] + ps[r];
#pragma unroll
      for (int n = 0; n < 8; ++n)
#pragma unroll
        for (int r = 0; r < 4; ++r) acc[n][r] *= scl[r];
      // ---- P -> LDS, read back as A-fragment ----
#pragma unroll
      for (int ktile = 0; ktile < 4; ++ktile)
#pragma unroll
        for (int r = 0; r < 4; ++r)
          P[wid][lg * 4 + r][ktile * 16 + lr] = f2bf(p[ktile][r]);
      asm volatile("s_waitcnt lgkmcnt(0)" ::: "memory");
      __builtin_amdgcn_sched_barrier(0);
      bf16x8 pf[2];
#pragma unroll
      for (int ks = 0; ks < 2; ++ks)
        pf[ks] = *(const bf16x8*)(&P[wid][lr][ks * 32 + lg * 8]);
#pragma unroll
      for (int n = 0; n < 8; ++n) {
        const int row = n * 16 + lr;
#pragma unroll
        for (int ks = 0; ks < 2; ++ks) {
          int chn = (ks * 4 + lg) ^ (lr & 7);
          bf16x8 vf = *(const bf16x8*)(Vs + row * 64 + chn * 8);
          acc[n] = __builtin_amdgcn_mfma_f32_16x16x32_bf16(pf[ks], vf, acc[n], 0, 0, 0);
        }
      }
    }
    __syncthreads();
  }

  // ---- write unnormalized partial O~ (bf16) + m,l (f32) ----
  unsigned short* pob = po + (size_t)slot * (128 * DD);
#pragma unroll
  for (int n = 0; n < 8; ++n)
#pragma unroll
    for (int r = 0; r < 4; ++r) {
      int row = wid * 16 + lg * 4 + r;
      pob[(size_t)row * DD + n * 16 + lr] = f2bf(acc[n][r]);
    }
  if (lr == 0) {
#pragma unroll
    for (int r = 0; r < 4; ++r) {
      int row = wid * 16 + lg * 4 + r;
      marr[(size_t)slot * 128 + row] = mrow[r];
      larr[(size_t)slot * 128 + row] = lsum[r];
    }
  }
}

// ---------------- split reduce: combine <=4 partials, normalize, emit bf16 ----------------
__global__ __launch_bounds__(256) void k_attn_reduce(
    const unsigned short* __restrict__ po, const float* __restrict__ marr,
    const float* __restrict__ larr, unsigned short* __restrict__ ob) {
  const int qt = blockIdx.x, h = blockIdx.y;
  const int ns = (qt >> 2) + 1;
  const int sb = h * 40 + soff(qt);
  const int tid = threadIdx.x;
  const int row = tid >> 1, d0 = (tid & 1) * 64;
  float mstar = -3e38f;
  for (int s = 0; s < ns; ++s) mstar = fmaxf(mstar, marr[(size_t)(sb + s) * 128 + row]);
  float w[4];
  float ltot = 0.f;
  for (int s = 0; s < ns; ++s) {
    w[s] = __expf(marr[(size_t)(sb + s) * 128 + row] - mstar);
    ltot += w[s] * larr[(size_t)(sb + s) * 128 + row];
  }
  float inv = 1.0f / ltot;
  float o[64] = {};
  for (int s = 0; s < ns; ++s) {
    const bf16x8* pp = (const bf16x8*)(po + (size_t)(sb + s) * (128 * DD) + (size_t)row * DD + d0);
    float ws = w[s];
#pragma unroll
    for (int j = 0; j < 8; ++j) {
      bf16x8 v = pp[j];
#pragma unroll
      for (int e = 0; e < 8; ++e) o[j * 8 + e] += ws * (float)v[e];
    }
  }
  unsigned short* op = ob + (size_t)(qt * 128 + row) * CC + h * DD + d0;
#pragma unroll
  for (int j = 0; j < 16; ++j) {
    us4 t = { f2bf(o[4 * j] * inv), f2bf(o[4 * j + 1] * inv),
              f2bf(o[4 * j + 2] * inv), f2bf(o[4 * j + 3] * inv) };
    ((us4*)op)[j] = t;
  }
}

// ---------------- row l2norm ----------------
__global__ __launch_bounds__(256) void k_l2norm(
    const float* __restrict__ Of, float* __restrict__ out) {
  const int t = blockIdx.x;
  const int tid = threadIdx.x;
  const float4* p = (const float4*)(Of + (size_t)t * CC);
  float4 a = p[2 * tid], b = p[2 * tid + 1];
  float ss = a.x * a.x + a.y * a.y + a.z * a.z + a.w * a.w +
             b.x * b.x + b.y * b.y + b.z * b.z + b.w * b.w;
#pragma unroll
  for (int msk = 1; msk < 64; msk <<= 1) ss += __shfl_xor(ss, msk);
  __shared__ float red[4];
  if ((tid & 63) == 0) red[tid >> 6] = ss;
  __syncthreads();
  ss = red[0] + red[1] + red[2] + red[3];
  float sc = 1.0f / fmaxf(sqrtf(ss), 1e-12f);
  float4 oa = { a.x * sc, a.y * sc, a.z * sc, a.w * sc };
  float4 obv = { b.x * sc, b.y * sc, b.z * sc, b.w * sc };
  float4* o = (float4*)(out + (size_t)t * CC);
  o[2 * tid] = oa;
  o[2 * tid + 1] = obv;
}

extern "C" void kernel_launch(void* const* d_in, const int* in_sizes, int n_in,
                              void* d_out, int out_size, void* d_ws, size_t ws_size,
                              hipStream_t stream) {
  const float* x   = (const float*)d_in[0];
  const float* wq  = (const float*)d_in[1];
  const float* wk  = (const float*)d_in[2];
  const float* wv  = (const float*)d_in[3];
  const float* wo  = (const float*)d_in[4];
  const float* sqk = (const float*)d_in[5];

  float* out_norm = (float*)d_out;
  float* out_k = out_norm + (size_t)4 * 1024 * 1024;
  float* out_v = out_norm + (size_t)8 * 1024 * 1024;

  char* ws = (char*)d_ws;
  unsigned short* xb  = (unsigned short*)(ws);                      // 0..8MB  (free after QKV)
  unsigned short* w1b = (unsigned short*)(ws + (8u << 20));         // 8..32MB (free after QKV)
  unsigned short* wob = (unsigned short*)(ws + (32u << 20));
  unsigned short* qb  = (unsigned short*)(ws + (40u << 20));
  unsigned short* kb  = (unsigned short*)(ws + (48u << 20));
  unsigned short* vtb = (unsigned short*)(ws + (56u << 20));
  unsigned short* obb = (unsigned short*)(ws + (64u << 20));
  float* Qf = (float*)(ws + (72u << 20));

  // attention split partials reuse 0..32MB (dead after QKV GEMM)
  unsigned short* po = (unsigned short*)(ws);                       // 640 slots * 32KB = 20MB
  float* marr = (float*)(ws + (22u << 20));                         // 320KB
  float* larr = (float*)(ws + (23u << 20));                         // 320KB

  const int n8 = (CC * CC) / 8;
  k_f32_to_bf16<<<n8 / 256, 256, 0, stream>>>(x,  xb, n8);
  k_f32_to_bf16<<<n8 / 256, 256, 0, stream>>>(wq, w1b, n8);
  k_f32_to_bf16<<<n8 / 256, 256, 0, stream>>>(wk, w1b + (size_t)4 * 1024 * 1024, n8);
  k_f32_to_bf16<<<n8 / 256, 256, 0, stream>>>(wv, w1b + (size_t)8 * 1024 * 1024, n8);
  k_f32_to_bf16<<<n8 / 256, 256, 0, stream>>>(wo, wob, n8);

  k_gemm_bt<0><<<dim3(48, 16), 256, 0, stream>>>(xb, w1b, TT, 3 * CC, CC, Qf, out_k, out_v);

  k_rope<<<TT, 256, 0, stream>>>(Qf, out_k, sqk, qb, kb);
  k_vt<<<dim3(32, 2, 16), 256, 0, stream>>>(out_v, vtb);

  k_attn_split<<<dim3(16, 16, 4), 512, 0, stream>>>(qb, kb, vtb, po, marr, larr);
  k_attn_reduce<<<dim3(16, 16), 256, 0, stream>>>(po, marr, larr, obb);

  k_gemm_bt<1><<<dim3(16, 16), 256, 0, stream>>>(obb, wob, TT, CC, CC, Qf, nullptr, nullptr);

  k_l2norm<<<TT, 256, 0, stream>>>(Qf, out_norm);
}

// Round 5
// 230.823 us; speedup vs baseline: 1.8567x; 1.1882x over previous
//
#include <hip/hip_runtime.h>

typedef __bf16 bf16x8 __attribute__((ext_vector_type(8)));
typedef float f32x4 __attribute__((ext_vector_type(4)));
typedef unsigned short us4 __attribute__((ext_vector_type(4)));

constexpr int TT = 2048;   // tokens
constexpr int CC = 2048;   // channels
constexpr int HH = 16;     // heads
constexpr int DD = 128;    // head dim

__device__ __forceinline__ unsigned short f2bf(float f) {
  unsigned u = __builtin_bit_cast(unsigned, f);
  u += 0x7FFFu + ((u >> 16) & 1u);
  return (unsigned short)(u >> 16);
}
__device__ __forceinline__ float bf2f(unsigned short b) {
  unsigned u = ((unsigned)b) << 16;
  return __builtin_bit_cast(float, u);
}

// async global->LDS, 16B per lane. C-style casts lower to addrspacecast.
__device__ __forceinline__ void gld_lds16(const unsigned short* g, unsigned short* l) {
  __builtin_amdgcn_global_load_lds(
      (const __attribute__((address_space(1))) unsigned int*)g,
      (__attribute__((address_space(3))) unsigned int*)l,
      16, 0, 0);
}

// split-slot table for QBLK=128, SPLIT=512 keys: ns(qt)=qt/4+1, 40 slots/head
__device__ __forceinline__ int soff(int qt) {
  int g = qt >> 2, rem = qt & 3;
  return (g + 1) * (2 * g + rem);
}

// ---------------- f32 -> bf16 convert ----------------
__global__ __launch_bounds__(256) void k_f32_to_bf16(
    const float* __restrict__ src, unsigned short* __restrict__ dst, int n8) {
  int i = blockIdx.x * 256 + threadIdx.x;
  if (i >= n8) return;
  const float4* s = (const float4*)src;
  float4 a = s[2 * i], b = s[2 * i + 1];
  us4 lo = { f2bf(a.x), f2bf(a.y), f2bf(a.z), f2bf(a.w) };
  us4 hi = { f2bf(b.x), f2bf(b.y), f2bf(b.z), f2bf(b.w) };
  us4* d = (us4*)dst;
  d[2 * i] = lo;
  d[2 * i + 1] = hi;
}

// ---------------- 256x256 8-phase GEMM: C = A(MxK) * B(NxK)^T ----------------
// 512 threads = 8 waves (2 M-rows x 4 N-cols), BK=64, double-buffered swizzled LDS.
// kspan selects a K-slice (split-K via blockIdx.z).
// MODE 0: fused QKV epilogue; MODE 1: f32 store to (z ? out1 : out0)[row*N+col].
template <int MODE>
__global__ __launch_bounds__(512, 2) void k_gemm256(
    const unsigned short* __restrict__ A, const unsigned short* __restrict__ B,
    int N, int K, int kspan,
    float* __restrict__ out0, float* __restrict__ out1, float* __restrict__ out2) {
  __shared__ alignas(16) unsigned short As[2][2][128 * 64];
  __shared__ alignas(16) unsigned short Bs[2][2][128 * 64];
  const int tid = threadIdx.x;
  const int m0 = blockIdx.y * 256, n0 = blockIdx.x * 256;
  const int kbeg = blockIdx.z * kspan;
  const int NT = kspan >> 6;
  const int wid = tid >> 6, lane = tid & 63;
  const int wr = wid >> 2, wc = wid & 3;
  const int lr = lane & 15, lg = lane >> 4;
  const int swz = lr & 7;

  // staging: chunk c = tid + j*512 of a 128x64 half-tile; row=c>>3, chunk-in-row=c&7
  const int sr = tid >> 3;
  const int sc = tid & 7;
  const int scs = (sc ^ (sr & 7)) * 8;  // pre-swizzled source column (rule #21)
  const unsigned short* a0 = A + (size_t)(m0 + sr) * K + kbeg + scs;
  const unsigned short* b0 = B + (size_t)(n0 + sr) * K + kbeg + scs;

  f32x4 acc[8][4] = {};
  bf16x8 av_lo[4][2], av_hi[4][2], bv_a[2][2], bv_b[2][2];

  const int bh = wc >> 1;             // B half this wave reads
  const int brow0 = (wc & 1) * 64;    // row base within that half

  // ---- prologue: stage K-tile 0 into buf 0 ----
#pragma unroll
  for (int h = 0; h < 2; ++h) {
    gld_lds16(a0 + (size_t)(h * 128) * K,      &As[0][h][tid * 8]);
    gld_lds16(a0 + (size_t)(h * 128 + 64) * K, &As[0][h][(tid + 512) * 8]);
    gld_lds16(b0 + (size_t)(h * 128) * K,      &Bs[0][h][tid * 8]);
    gld_lds16(b0 + (size_t)(h * 128 + 64) * K, &Bs[0][h][(tid + 512) * 8]);
  }
  asm volatile("s_waitcnt vmcnt(0)" ::: "memory");
  __builtin_amdgcn_sched_barrier(0);
  __builtin_amdgcn_s_barrier();

  for (int t = 0; t < NT; ++t) {
    const int cur = t & 1, nxt = cur ^ 1;
    const int k0n = (t + 1) * 64;
    const bool pf = (t + 1) < NT;

    // ================= phase 1: read A-lo + B-a ; stage A(next) =================
#pragma unroll
    for (int im = 0; im < 4; ++im)
#pragma unroll
      for (int kk = 0; kk < 2; ++kk)
        av_lo[im][kk] = *(const bf16x8*)(&As[cur][wr][(im * 16 + lr) * 64 + (((kk * 4 + lg) ^ swz) * 8)]);
#pragma unroll
    for (int in = 0; in < 2; ++in)
#pragma unroll
      for (int kk = 0; kk < 2; ++kk)
        bv_a[in][kk] = *(const bf16x8*)(&Bs[cur][bh][(brow0 + in * 16 + lr) * 64 + (((kk * 4 + lg) ^ swz) * 8)]);
    if (pf) {
      gld_lds16(a0 + k0n,                       &As[nxt][0][tid * 8]);
      gld_lds16(a0 + (size_t)64 * K + k0n,      &As[nxt][0][(tid + 512) * 8]);
      gld_lds16(a0 + (size_t)128 * K + k0n,     &As[nxt][1][tid * 8]);
      gld_lds16(a0 + (size_t)192 * K + k0n,     &As[nxt][1][(tid + 512) * 8]);
    }
    __builtin_amdgcn_s_barrier();
    asm volatile("s_waitcnt lgkmcnt(0)" ::: "memory");
    __builtin_amdgcn_sched_barrier(0);
    __builtin_amdgcn_s_setprio(1);
#pragma unroll
    for (int im = 0; im < 4; ++im)
#pragma unroll
      for (int in = 0; in < 2; ++in)
#pragma unroll
        for (int kk = 0; kk < 2; ++kk)
          acc[im][in] = __builtin_amdgcn_mfma_f32_16x16x32_bf16(av_lo[im][kk], bv_a[in][kk], acc[im][in], 0, 0, 0);
    __builtin_amdgcn_s_setprio(0);
    __builtin_amdgcn_sched_barrier(0);
    __builtin_amdgcn_s_barrier();

    // ================= phase 2: read B-b ; stage B-h0(next) =================
#pragma unroll
    for (int in = 0; in < 2; ++in)
#pragma unroll
      for (int kk = 0; kk < 2; ++kk)
        bv_b[in][kk] = *(const bf16x8*)(&Bs[cur][bh][(brow0 + (2 + in) * 16 + lr) * 64 + (((kk * 4 + lg) ^ swz) * 8)]);
    if (pf) {
      gld_lds16(b0 + k0n,                   &Bs[nxt][0][tid * 8]);
      gld_lds16(b0 + (size_t)64 * K + k0n,  &Bs[nxt][0][(tid + 512) * 8]);
    }
    __builtin_amdgcn_s_barrier();
    asm volatile("s_waitcnt lgkmcnt(0)" ::: "memory");
    __builtin_amdgcn_sched_barrier(0);
    __builtin_amdgcn_s_setprio(1);
#pragma unroll
    for (int im = 0; im < 4; ++im)
#pragma unroll
      for (int in = 0; in < 2; ++in)
#pragma unroll
        for (int kk = 0; kk < 2; ++kk)
          acc[im][2 + in] = __builtin_amdgcn_mfma_f32_16x16x32_bf16(av_lo[im][kk], bv_b[in][kk], acc[im][2 + in], 0, 0, 0);
    __builtin_amdgcn_s_setprio(0);
    __builtin_amdgcn_sched_barrier(0);
    __builtin_amdgcn_s_barrier();

    // ================= phase 3: read A-hi ; stage B-h1(next) =================
#pragma unroll
    for (int im = 0; im < 4; ++im)
#pragma unroll
      for (int kk = 0; kk < 2; ++kk)
        av_hi[im][kk] = *(const bf16x8*)(&As[cur][wr][((4 + im) * 16 + lr) * 64 + (((kk * 4 + lg) ^ swz) * 8)]);
    if (pf) {
      gld_lds16(b0 + (size_t)128 * K + k0n, &Bs[nxt][1][tid * 8]);
      gld_lds16(b0 + (size_t)192 * K + k0n, &Bs[nxt][1][(tid + 512) * 8]);
    }
    __builtin_amdgcn_s_barrier();
    asm volatile("s_waitcnt lgkmcnt(0)" ::: "memory");
    __builtin_amdgcn_sched_barrier(0);
    __builtin_amdgcn_s_setprio(1);
#pragma unroll
    for (int im = 0; im < 4; ++im)
#pragma unroll
      for (int in = 0; in < 2; ++in)
#pragma unroll
        for (int kk = 0; kk < 2; ++kk)
          acc[4 + im][2 + in] = __builtin_amdgcn_mfma_f32_16x16x32_bf16(av_hi[im][kk], bv_b[in][kk], acc[4 + im][2 + in], 0, 0, 0);
    __builtin_amdgcn_s_setprio(0);
    __builtin_amdgcn_sched_barrier(0);
    __builtin_amdgcn_s_barrier();

    // ================= phase 4: MFMA hi x a ; drain stage loads =================
#pragma unroll
    for (int im = 0; im < 4; ++im)
#pragma unroll
      for (int in = 0; in < 2; ++in)
#pragma unroll
        for (int kk = 0; kk < 2; ++kk)
          acc[4 + im][in] = __builtin_amdgcn_mfma_f32_16x16x32_bf16(av_hi[im][kk], bv_a[in][kk], acc[4 + im][in], 0, 0, 0);
    asm volatile("s_waitcnt vmcnt(0)" ::: "memory");
    __builtin_amdgcn_sched_barrier(0);
    __builtin_amdgcn_s_barrier();
  }

  // ---- epilogue ----
  float* dst = (MODE == 1 && blockIdx.z) ? out1 : out0;
#pragma unroll
  for (int mf = 0; mf < 8; ++mf) {
    const int row = m0 + wr * 128 + mf * 16 + lg * 4;
#pragma unroll
    for (int nf = 0; nf < 4; ++nf) {
      const int col = n0 + wc * 64 + nf * 16 + lr;
#pragma unroll
      for (int r = 0; r < 4; ++r) {
        float v = acc[mf][nf][r];
        int rr = row + r;
        if (MODE == 0) {
          if (col < 2048) {
            out0[(size_t)rr * 2048 + col] = v;
          } else if (col < 4096) {
            int c = col - 2048;
            out1[(size_t)(c >> 7) * (TT * DD) + (size_t)rr * DD + (c & 127)] = v;
          } else {
            int c = col - 4096;
            out2[(size_t)(c >> 7) * (TT * DD) + (size_t)rr * DD + (c & 127)] = v;
          }
        } else {
          dst[(size_t)rr * N + col] = v;
        }
      }
    }
  }
}

// ---------------- RoPE + scale, pack q/k as bf16 [h][t][d] ----------------
__global__ __launch_bounds__(256) void k_rope(
    const float* __restrict__ Qf, const float* __restrict__ Kraw,
    const float* __restrict__ sqk,
    unsigned short* __restrict__ qb, unsigned short* __restrict__ kb) {
  const int t = blockIdx.x;
  for (int i = threadIdx.x; i < HH * 64; i += 256) {
    int h = i >> 6, dp = i & 63;
    float theta = expf(-(float)dp * 0.14391156831212787f);
    float ang = (float)t * theta;
    float sn, cs;
    sincosf(ang, &sn, &cs);
    float qr = Qf[(size_t)t * CC + h * DD + dp];
    float qi = Qf[(size_t)t * CC + h * DD + dp + 64];
    const float* kp = Kraw + (size_t)h * TT * DD + (size_t)t * DD;
    float kr = kp[dp], ki = kp[dp + 64];
    float sr = sqk[h * DD + dp];
    float si = sqk[h * DD + dp + 64];
    float qsr = sr * 512.0f, qsi = si * 512.0f;                         // sqrt(C)*sqrt(D)
    float ksr = sr * 45.25483399593904f, ksi = si * 45.25483399593904f; // sqrt(C)
    unsigned short* qo = qb + ((size_t)h * TT + t) * DD;
    unsigned short* ko = kb + ((size_t)h * TT + t) * DD;
    qo[dp]      = f2bf((qr * cs - qi * sn) * qsr);
    qo[dp + 64] = f2bf((qr * sn + qi * cs) * qsi);
    ko[dp]      = f2bf((kr * cs - ki * sn) * ksr);
    ko[dp + 64] = f2bf((kr * sn + ki * cs) * ksi);
  }
}

// ---------------- V transpose: new_v f32 [h][t][d] -> vt bf16 [h][d][t] ----------------
__global__ __launch_bounds__(256) void k_vt(
    const float* __restrict__ Vraw, unsigned short* __restrict__ vt) {
  const int h = blockIdx.z;
  const int t0 = blockIdx.x * 64, d0 = blockIdx.y * 64;
  __shared__ unsigned short tile[64][65];
  const float* vp = Vraw + (size_t)h * TT * DD;
  for (int i = threadIdx.x; i < 4096; i += 256) {
    int r = i >> 6, c = i & 63;
    tile[r][c] = f2bf(vp[(size_t)(t0 + r) * DD + d0 + c]);
  }
  __syncthreads();
  unsigned short* op = vt + (size_t)h * DD * TT;
  for (int i = threadIdx.x; i < 4096; i += 256) {
    int dr = i >> 6, tc = i & 63;
    op[(size_t)(d0 + dr) * TT + t0 + tc] = tile[tc][dr];
  }
}

// ---------------- causal flash attention, 8-wave LDS-staged, split-K ----------------
__global__ __launch_bounds__(512) void k_attn_split(
    const unsigned short* __restrict__ qb, const unsigned short* __restrict__ kb,
    const unsigned short* __restrict__ vt,
    unsigned short* __restrict__ po, float* __restrict__ marr, float* __restrict__ larr) {
  const int qt = blockIdx.x, h = blockIdx.y, s = blockIdx.z;
  if (4 * s > qt) return;
  const int slot = h * 40 + soff(qt) + s;
  const int kbeg = 512 * s;
  const int kend = min(kbeg + 512, 128 * qt + 128);
  const int ntiles = (kend - kbeg) >> 6;
  const int tid = threadIdx.x;
  const int wid = tid >> 6, lane = tid & 63;
  const int lr = lane & 15, lg = lane >> 4;
  const int q0 = qt * 128 + wid * 16;

  __shared__ alignas(16) unsigned short Ks[64 * 128];
  __shared__ alignas(16) unsigned short Vs[128 * 64];
  __shared__ alignas(16) unsigned short P[8][16][72];

  const unsigned short* qh = qb + (size_t)h * TT * DD;
  const unsigned short* kh = kb + (size_t)h * TT * DD;
  const unsigned short* vh = vt + (size_t)h * DD * TT;

  bf16x8 qf[4];
#pragma unroll
  for (int c = 0; c < 4; ++c)
    qf[c] = *(const bf16x8*)(qh + (size_t)(q0 + lr) * DD + c * 32 + lg * 8);

  f32x4 acc[8] = {};
  float mrow[4] = {-3e38f, -3e38f, -3e38f, -3e38f};
  float lsum[4] = {0.f, 0.f, 0.f, 0.f};

  for (int kt = 0; kt < ntiles; ++kt) {
    const int k0 = kbeg + kt * 64;
#pragma unroll
    for (int half = 0; half < 2; ++half) {
      int ch = tid + half * 512;
      int r = ch >> 4, c4 = ch & 15;
      gld_lds16(kh + (size_t)(k0 + r) * DD + ((c4 ^ (r & 7)) * 8), Ks + ch * 8);
    }
#pragma unroll
    for (int half = 0; half < 2; ++half) {
      int ch = tid + half * 512;
      int d = ch >> 3, c8 = ch & 7;
      gld_lds16(vh + (size_t)d * TT + k0 + ((c8 ^ (d & 7)) * 8), Vs + ch * 8);
    }
    __syncthreads();

    if (k0 <= q0 + 15) {
      f32x4 sv[4] = {};
#pragma unroll
      for (int ktile = 0; ktile < 4; ++ktile) {
        const int row = ktile * 16 + lr;
#pragma unroll
        for (int c = 0; c < 4; ++c) {
          int chn = (c * 4 + lg) ^ (lr & 7);
          bf16x8 kf = *(const bf16x8*)(Ks + row * 128 + chn * 8);
          sv[ktile] = __builtin_amdgcn_mfma_f32_16x16x32_bf16(qf[c], kf, sv[ktile], 0, 0, 0);
        }
      }
      if (k0 + 63 > q0) {
#pragma unroll
        for (int ktile = 0; ktile < 4; ++ktile)
#pragma unroll
          for (int r = 0; r < 4; ++r) {
            int key = k0 + ktile * 16 + lr;
            int qrow = q0 + lg * 4 + r;
            if (key > qrow) sv[ktile][r] = -1e30f;
          }
      }
      float pmax[4];
#pragma unroll
      for (int r = 0; r < 4; ++r)
        pmax[r] = fmaxf(fmaxf(sv[0][r], sv[1][r]), fmaxf(sv[2][r], sv[3][r]));
#pragma unroll
      for (int msk = 1; msk <= 8; msk <<= 1)
#pragma unroll
        for (int r = 0; r < 4; ++r) pmax[r] = fmaxf(pmax[r], __shfl_xor(pmax[r], msk));
      float p[4][4], ps[4], scl[4];
#pragma unroll
      for (int r = 0; r < 4; ++r) {
        float mn = fmaxf(mrow[r], pmax[r]);
        scl[r] = __expf(mrow[r] - mn);
        mrow[r] = mn;
        ps[r] = 0.f;
#pragma unroll
        for (int ktile = 0; ktile < 4; ++ktile) {
          p[ktile][r] = __expf(sv[ktile][r] - mn);
          ps[r] += p[ktile][r];
        }
      }
#pragma unroll
      for (int msk = 1; msk <= 8; msk <<= 1)
#pragma unroll
        for (int r = 0; r < 4; ++r) ps[r] += __shfl_xor(ps[r], msk);
#pragma unroll
      for (int r = 0; r < 4; ++r) lsum[r] = lsum[r] * scl[r] + ps[r];
#pragma unroll
      for (int n = 0; n < 8; ++n)
#pragma unroll
        for (int r = 0; r < 4; ++r) acc[n][r] *= scl[r];
#pragma unroll
      for (int ktile = 0; ktile < 4; ++ktile)
#pragma unroll
        for (int r = 0; r < 4; ++r)
          P[wid][lg * 4 + r][ktile * 16 + lr] = f2bf(p[ktile][r]);
      asm volatile("s_waitcnt lgkmcnt(0)" ::: "memory");
      __builtin_amdgcn_sched_barrier(0);
      bf16x8 pf[2];
#pragma unroll
      for (int ks = 0; ks < 2; ++ks)
        pf[ks] = *(const bf16x8*)(&P[wid][lr][ks * 32 + lg * 8]);
#pragma unroll
      for (int n = 0; n < 8; ++n) {
        const int row = n * 16 + lr;
#pragma unroll
        for (int ks = 0; ks < 2; ++ks) {
          int chn = (ks * 4 + lg) ^ (lr & 7);
          bf16x8 vf = *(const bf16x8*)(Vs + row * 64 + chn * 8);
          acc[n] = __builtin_amdgcn_mfma_f32_16x16x32_bf16(pf[ks], vf, acc[n], 0, 0, 0);
        }
      }
    }
    __syncthreads();
  }

  unsigned short* pob = po + (size_t)slot * (128 * DD);
#pragma unroll
  for (int n = 0; n < 8; ++n)
#pragma unroll
    for (int r = 0; r < 4; ++r) {
      int row = wid * 16 + lg * 4 + r;
      pob[(size_t)row * DD + n * 16 + lr] = f2bf(acc[n][r]);
    }
  if (lr == 0) {
#pragma unroll
    for (int r = 0; r < 4; ++r) {
      int row = wid * 16 + lg * 4 + r;
      marr[(size_t)slot * 128 + row] = mrow[r];
      larr[(size_t)slot * 128 + row] = lsum[r];
    }
  }
}

// ---------------- split reduce ----------------
__global__ __launch_bounds__(256) void k_attn_reduce(
    const unsigned short* __restrict__ po, const float* __restrict__ marr,
    const float* __restrict__ larr, unsigned short* __restrict__ ob) {
  const int qt = blockIdx.x, h = blockIdx.y;
  const int ns = (qt >> 2) + 1;
  const int sb = h * 40 + soff(qt);
  const int tid = threadIdx.x;
  const int row = tid >> 1, d0 = (tid & 1) * 64;
  float mstar = -3e38f;
  for (int s = 0; s < ns; ++s) mstar = fmaxf(mstar, marr[(size_t)(sb + s) * 128 + row]);
  float w[4];
  float ltot = 0.f;
  for (int s = 0; s < ns; ++s) {
    w[s] = __expf(marr[(size_t)(sb + s) * 128 + row] - mstar);
    ltot += w[s] * larr[(size_t)(sb + s) * 128 + row];
  }
  float inv = 1.0f / ltot;
  float o[64] = {};
  for (int s = 0; s < ns; ++s) {
    const bf16x8* pp = (const bf16x8*)(po + (size_t)(sb + s) * (128 * DD) + (size_t)row * DD + d0);
    float ws = w[s];
#pragma unroll
    for (int j = 0; j < 8; ++j) {
      bf16x8 v = pp[j];
#pragma unroll
      for (int e = 0; e < 8; ++e) o[j * 8 + e] += ws * (float)v[e];
    }
  }
  unsigned short* op = ob + (size_t)(qt * 128 + row) * CC + h * DD + d0;
#pragma unroll
  for (int j = 0; j < 16; ++j) {
    us4 t = { f2bf(o[4 * j] * inv), f2bf(o[4 * j + 1] * inv),
              f2bf(o[4 * j + 2] * inv), f2bf(o[4 * j + 3] * inv) };
    ((us4*)op)[j] = t;
  }
}

// ---------------- row l2norm over sum of two split-K partials ----------------
__global__ __launch_bounds__(256) void k_l2norm(
    const float* __restrict__ Of0, const float* __restrict__ Of1, float* __restrict__ out) {
  const int t = blockIdx.x;
  const int tid = threadIdx.x;
  const float4* p0 = (const float4*)(Of0 + (size_t)t * CC);
  const float4* p1 = (const float4*)(Of1 + (size_t)t * CC);
  float4 a = p0[2 * tid], b = p0[2 * tid + 1];
  float4 a1 = p1[2 * tid], b1 = p1[2 * tid + 1];
  a.x += a1.x; a.y += a1.y; a.z += a1.z; a.w += a1.w;
  b.x += b1.x; b.y += b1.y; b.z += b1.z; b.w += b1.w;
  float ss = a.x * a.x + a.y * a.y + a.z * a.z + a.w * a.w +
             b.x * b.x + b.y * b.y + b.z * b.z + b.w * b.w;
#pragma unroll
  for (int msk = 1; msk < 64; msk <<= 1) ss += __shfl_xor(ss, msk);
  __shared__ float red[4];
  if ((tid & 63) == 0) red[tid >> 6] = ss;
  __syncthreads();
  ss = red[0] + red[1] + red[2] + red[3];
  float sc = 1.0f / fmaxf(sqrtf(ss), 1e-12f);
  float4 oa = { a.x * sc, a.y * sc, a.z * sc, a.w * sc };
  float4 obv = { b.x * sc, b.y * sc, b.z * sc, b.w * sc };
  float4* o = (float4*)(out + (size_t)t * CC);
  o[2 * tid] = oa;
  o[2 * tid + 1] = obv;
}

extern "C" void kernel_launch(void* const* d_in, const int* in_sizes, int n_in,
                              void* d_out, int out_size, void* d_ws, size_t ws_size,
                              hipStream_t stream) {
  const float* x   = (const float*)d_in[0];
  const float* wq  = (const float*)d_in[1];
  const float* wk  = (const float*)d_in[2];
  const float* wv  = (const float*)d_in[3];
  const float* wo  = (const float*)d_in[4];
  const float* sqk = (const float*)d_in[5];

  float* out_norm = (float*)d_out;
  float* out_k = out_norm + (size_t)4 * 1024 * 1024;
  float* out_v = out_norm + (size_t)8 * 1024 * 1024;

  char* ws = (char*)d_ws;
  unsigned short* xb  = (unsigned short*)(ws);                      // 0..8MB  (dead after QKV)
  unsigned short* w1b = (unsigned short*)(ws + (8u << 20));         // 8..32MB (dead after QKV)
  unsigned short* wob = (unsigned short*)(ws + (32u << 20));        // 32..40MB
  unsigned short* qb  = (unsigned short*)(ws + (40u << 20));        // 40..48MB
  unsigned short* kb  = (unsigned short*)(ws + (48u << 20));        // 48..56MB
  unsigned short* vtb = (unsigned short*)(ws + (56u << 20));        // 56..64MB
  unsigned short* obb = (unsigned short*)(ws + (64u << 20));        // 64..72MB
  float* Qf = (float*)(ws + (72u << 20));                           // 72..88MB (Q f32)

  // attention split partials reuse 0..24MB (dead after QKV GEMM)
  unsigned short* po = (unsigned short*)(ws);                       // 640 slots * 32KB = 20MB
  float* marr = (float*)(ws + (22u << 20));
  float* larr = (float*)(ws + (23u << 20));

  // out-proj split-K partials: Of0 reuses Qf (dead after rope), Of1 reuses 0..16MB (po dead)
  float* Of0 = Qf;
  float* Of1 = (float*)(ws);

  const int n8 = (CC * CC) / 8;
  k_f32_to_bf16<<<n8 / 256, 256, 0, stream>>>(x,  xb, n8);
  k_f32_to_bf16<<<n8 / 256, 256, 0, stream>>>(wq, w1b, n8);
  k_f32_to_bf16<<<n8 / 256, 256, 0, stream>>>(wk, w1b + (size_t)4 * 1024 * 1024, n8);
  k_f32_to_bf16<<<n8 / 256, 256, 0, stream>>>(wv, w1b + (size_t)8 * 1024 * 1024, n8);
  k_f32_to_bf16<<<n8 / 256, 256, 0, stream>>>(wo, wob, n8);

  // fused QKV projection: 2048 x 6144 x 2048, 256^2 8-phase
  k_gemm256<0><<<dim3(24, 8, 1), 512, 0, stream>>>(xb, w1b, 3 * CC, CC, CC, Qf, out_k, out_v);

  k_rope<<<TT, 256, 0, stream>>>(Qf, out_k, sqk, qb, kb);
  k_vt<<<dim3(32, 2, 16), 256, 0, stream>>>(out_v, vtb);

  k_attn_split<<<dim3(16, 16, 4), 512, 0, stream>>>(qb, kb, vtb, po, marr, larr);
  k_attn_reduce<<<dim3(16, 16), 256, 0, stream>>>(po, marr, larr, obb);

  // output projection: 2048 x 2048 x 2048, split-K=2 (z), partials f32
  k_gemm256<1><<<dim3(8, 8, 2), 512, 0, stream>>>(obb, wob, CC, CC, CC / 2, Of0, Of1, nullptr);

  k_l2norm<<<TT, 256, 0, stream>>>(Of0, Of1, out_norm);
}